// Round 3
// baseline (1719.634 us; speedup 1.0000x reference)
//
#include <hip/hip_runtime.h>

#define NTOK  32768   // 8*4096 tokens
#define NE    8192    // codebook size
#define DIM   256     // embedding dim
#define BT    128     // token tile
#define BE    128     // code tile
#define BK    32      // k chunk
#define LDW   132     // padded LDS leading dim

// ws layout: e2[8192] f32 @0 ; z2[32768] f32 @32KB ; k1[32768] u64 @256KB
// out layout: zq[8388608] ; loss[1] ; idx[32768] (as float)

static __device__ __forceinline__ unsigned long long pack_key(float s, int idx) {
  unsigned u = __float_as_uint(s);
  u = (u & 0x80000000u) ? ~u : (u | 0x80000000u);   // order-preserving map
  return ((unsigned long long)u << 32) | (unsigned)idx;
}

// kernel 0: numpy-pairwise-exact row sums of squares for z (32768 rows) and
// emb (8192 rows); also init keys and zero the loss slot.
// numpy tree for n=256: pairwise(a,128)+pairwise(a+128,128); each 128-block:
// r[j] = sum_{t=0..15} x[j+8t] (sequential), res=((r0+r1)+(r2+r3))+((r4+r5)+(r6+r7)).
// 16 rows per wave: lane = 4 per row; sub bit0=q (acc quad), bit1=h (half).
__global__ __launch_bounds__(256) void vq_init(const float* __restrict__ z,
                                               const float* __restrict__ emb,
                                               float* __restrict__ e2,
                                               float* __restrict__ z2,
                                               unsigned long long* __restrict__ k1,
                                               float* __restrict__ loss_slot) {
  int gid = blockIdx.x * 256 + threadIdx.x;
  if (gid < NTOK) k1[gid] = ~0ull;
  if (gid == 0) loss_slot[0] = 0.0f;

  int wave = gid >> 6;
  int lane = threadIdx.x & 63;
  int row = wave * 16 + (lane >> 2);            // 0..40959
  int sub = lane & 3;
  int q = sub & 1, h = sub >> 1;

  const float* src = (row < NTOK) ? (z + (size_t)row * DIM)
                                  : (emb + (size_t)(row - NTOK) * DIM);
  const float4* p = reinterpret_cast<const float4*>(src + h * 128 + q * 4);

  float r0, r1, r2, r3, s;
  {
    #pragma clang fp contract(off)
    r0 = 0.0f; r1 = 0.0f; r2 = 0.0f; r3 = 0.0f;
    #pragma unroll
    for (int t = 0; t < 16; t++) {
      float4 v = p[2 * t];                      // elements j..j+3 at step t
      float q0 = v.x * v.x, q1 = v.y * v.y, q2 = v.z * v.z, q3 = v.w * v.w;
      r0 = r0 + q0; r1 = r1 + q1; r2 = r2 + q2; r3 = r3 + q3;
    }
    s = (r0 + r1) + (r2 + r3);                  // quad combine (exact tree piece)
    s = s + __shfl_xor(s, 1, 64);               // q combine: (r0..r3)+(r4..r7)
    s = s + __shfl_xor(s, 2, 64);               // half combine: block0+block1
  }
  if (sub == 0) {
    if (row < NTOK) z2[row] = s;
    else           e2[row - NTOK] = s;
  }
}

// kernel 1: fp32 GEMM m = (2z).emb^T (ascending-k single fma chain, sgemm
// semantics) + numpy-exact score s = fp32(fp32(z2 - m) + e2), top-1 argmin.
__global__ __launch_bounds__(256, 4) void vq_score(const float* __restrict__ z,
                                                   const float* __restrict__ emb,
                                                   const float* __restrict__ e2,
                                                   const float* __restrict__ z2,
                                                   unsigned long long* __restrict__ k1) {
  __shared__ float As[BK][LDW];                 // holds 2*z (exact scaling)
  __shared__ float Bs[BK][LDW];
  __shared__ unsigned long long mkey[BT];

  const int tid = threadIdx.x;
  const int t0 = blockIdx.x * BT;
  const int e0 = blockIdx.y * BE;
  const int tx = tid & 15;                      // code group (8 codes)
  const int ty = tid >> 4;                      // token group (8 tokens)

  if (tid < BT) mkey[tid] = ~0ull;

  float acc[8][8];
  #pragma unroll
  for (int i = 0; i < 8; i++)
    #pragma unroll
    for (int j = 0; j < 8; j++) acc[i][j] = 0.0f;

  const float* __restrict__ zt = z + (size_t)t0 * DIM;
  const float* __restrict__ et = emb + (size_t)e0 * DIM;

  for (int kc = 0; kc < DIM; kc += BK) {
    __syncthreads();
    #pragma unroll
    for (int i = 0; i < 4; i++) {
      int f = tid + i * 256;
      int row = f >> 3;
      int kq = f & 7;
      const float4 va = *reinterpret_cast<const float4*>(zt + row * DIM + kc + kq * 4);
      const float4 vb = *reinterpret_cast<const float4*>(et + row * DIM + kc + kq * 4);
      int k = kq * 4;
      As[k + 0][row] = va.x * 2.0f; As[k + 1][row] = va.y * 2.0f;
      As[k + 2][row] = va.z * 2.0f; As[k + 3][row] = va.w * 2.0f;
      Bs[k + 0][row] = vb.x; Bs[k + 1][row] = vb.y;
      Bs[k + 2][row] = vb.z; Bs[k + 3][row] = vb.w;
    }
    __syncthreads();
    #pragma unroll 4
    for (int k = 0; k < BK; k++) {
      float a[8], b[8];
      *(float4*)&a[0] = *(const float4*)&As[k][ty * 8];
      *(float4*)&a[4] = *(const float4*)&As[k][ty * 8 + 4];
      *(float4*)&b[0] = *(const float4*)&Bs[k][tx * 8];
      *(float4*)&b[4] = *(const float4*)&Bs[k][tx * 8 + 4];
      #pragma unroll
      for (int i = 0; i < 8; i++)
        #pragma unroll
        for (int j = 0; j < 8; j++)
          acc[i][j] = fmaf(a[i], b[j], acc[i][j]);   // ascending-k single chain
    }
  }

  float e2c[8], z2t[8];
  *(float4*)&e2c[0] = *(const float4*)(e2 + e0 + tx * 8);
  *(float4*)&e2c[4] = *(const float4*)(e2 + e0 + tx * 8 + 4);
  *(float4*)&z2t[0] = *(const float4*)(z2 + t0 + ty * 8);
  *(float4*)&z2t[4] = *(const float4*)(z2 + t0 + ty * 8 + 4);

  {
    #pragma clang fp contract(off)
    #pragma unroll
    for (int i = 0; i < 8; i++) {
      int trow = ty * 8 + i;
      unsigned long long best = ~0ull;
      #pragma unroll
      for (int j = 0; j < 8; j++) {
        float t1 = z2t[i] - acc[i][j];          // fp32 round (z2 - M)
        float s = t1 + e2c[j];                  // fp32 round (+ e2)
        unsigned long long kk = pack_key(s, e0 + tx * 8 + j);
        best = kk < best ? kk : best;
      }
      atomicMin(&mkey[trow], best);
    }
  }
  __syncthreads();
  if (tid < BT) atomicMin(&k1[t0 + tid], mkey[tid]);
}

// kernel 2: gather zq = emb[idx], write idx as float, accumulate loss
__global__ __launch_bounds__(256) void vq_out(const float* __restrict__ z,
                                              const float* __restrict__ emb,
                                              const unsigned long long* __restrict__ k1,
                                              float* __restrict__ out_zq,
                                              float* __restrict__ out_loss,
                                              float* __restrict__ out_idx) {
  __shared__ float lsum[4];
  const int wid = threadIdx.x >> 6;
  const int lane = threadIdx.x & 63;
  const int tbase = blockIdx.x * 16 + wid * 4;   // 16 tokens/block, 4/wave
  float s_acc = 0.0f;
  #pragma unroll
  for (int it = 0; it < 4; it++) {
    int t = tbase + it;
    unsigned idx = (unsigned)(k1[t] & 0xffffffffu);
    float4 e = reinterpret_cast<const float4*>(emb + (size_t)idx * DIM)[lane];
    float4 zz = reinterpret_cast<const float4*>(z + (size_t)t * DIM)[lane];
    reinterpret_cast<float4*>(out_zq + (size_t)t * DIM)[lane] = e;
    float dx = e.x - zz.x, dy = e.y - zz.y, dz = e.z - zz.z, dw = e.w - zz.w;
    s_acc += dx * dx + dy * dy + dz * dz + dw * dw;
    if (lane == 0) out_idx[t] = (float)idx;
  }
  #pragma unroll
  for (int off = 32; off > 0; off >>= 1) s_acc += __shfl_down(s_acc, off, 64);
  if (lane == 0) lsum[wid] = s_acc;
  __syncthreads();
  if (threadIdx.x == 0) {
    float tot = (lsum[0] + lsum[1] + lsum[2] + lsum[3]) * (1.25f / 8388608.0f);
    atomicAdd(out_loss, tot);
  }
}

extern "C" void kernel_launch(void* const* d_in, const int* in_sizes, int n_in,
                              void* d_out, int out_size, void* d_ws, size_t ws_size,
                              hipStream_t stream) {
  const float* z = (const float*)d_in[0];
  const float* emb = (const float*)d_in[1];
  float* out = (float*)d_out;
  float* out_zq = out;
  float* out_loss = out + (size_t)NTOK * DIM;    // element 8388608
  float* out_idx = out_loss + 1;
  float* e2 = (float*)d_ws;                                  // 32 KB
  float* z2 = (float*)((char*)d_ws + 32768);                 // 128 KB
  unsigned long long* k1 = (unsigned long long*)((char*)d_ws + 262144);  // 256 KB

  hipLaunchKernelGGL(vq_init, dim3(640), dim3(256), 0, stream,
                     z, emb, e2, z2, k1, out_loss);
  hipLaunchKernelGGL(vq_score, dim3(NTOK / BT, NE / BE), dim3(256), 0, stream,
                     z, emb, e2, z2, k1);
  hipLaunchKernelGGL(vq_out, dim3(NTOK / 16), dim3(256), 0, stream,
                     z, emb, k1, out_zq, out_loss, out_idx);
}